// Round 1
// baseline (630.858 us; speedup 1.0000x reference)
//
#include <hip/hip_runtime.h>

#define N_NODES 50000
#define N_EDGES 800000
#define N_GRAPHS 50
#define D 128
#define D_OUT 10

// ---------------------------------------------------------------------------
// 1) Degree histograms: cnt_dst (in-deg, becomes CSR row counts), cnt_src (out-deg)
// ---------------------------------------------------------------------------
__global__ __launch_bounds__(256) void hist_edges(const int* __restrict__ src,
                                                  const int* __restrict__ dst,
                                                  int* __restrict__ cnt_dst,
                                                  int* __restrict__ cnt_src) {
    int i = blockIdx.x * 256 + threadIdx.x;
    if (i < N_EDGES) {
        atomicAdd(&cnt_dst[dst[i]], 1);
        atomicAdd(&cnt_src[src[i]], 1);
    }
}

// ---------------------------------------------------------------------------
// 2) Single-block exclusive scan of cnt -> row_ptr (and fill copy for scatter)
//    1024 threads, 4 elems/thread, wave-shuffle scan (tiles of 4096)
// ---------------------------------------------------------------------------
__global__ __launch_bounds__(1024) void scan_k(const int* __restrict__ cnt,
                                               int* __restrict__ row_ptr,
                                               int* __restrict__ fill) {
    __shared__ int wsum[16];
    __shared__ int carry_s;
    int tid = threadIdx.x;
    int lane = tid & 63, wid = tid >> 6;
    if (tid == 0) carry_s = 0;
    __syncthreads();
    for (int base = 0; base < N_NODES; base += 4096) {
        int i0 = base + tid * 4;
        int v0 = (i0 + 0 < N_NODES) ? cnt[i0 + 0] : 0;
        int v1 = (i0 + 1 < N_NODES) ? cnt[i0 + 1] : 0;
        int v2 = (i0 + 2 < N_NODES) ? cnt[i0 + 2] : 0;
        int v3 = (i0 + 3 < N_NODES) ? cnt[i0 + 3] : 0;
        int s = v0 + v1 + v2 + v3;
        int x = s;
        #pragma unroll
        for (int d = 1; d < 64; d <<= 1) {
            int y = __shfl_up(x, d, 64);
            if (lane >= d) x += y;
        }
        if (lane == 63) wsum[wid] = x;
        __syncthreads();
        if (wid == 0) {
            int t = (lane < 16) ? wsum[lane] : 0;
            #pragma unroll
            for (int d = 1; d < 16; d <<= 1) {
                int y = __shfl_up(t, d, 64);
                if (lane >= d) t += y;
            }
            if (lane < 16) wsum[lane] = t;
        }
        __syncthreads();
        int woff = (wid == 0) ? 0 : wsum[wid - 1];
        int excl = carry_s + woff + (x - s);
        int run = excl;
        if (i0 + 0 < N_NODES) { row_ptr[i0 + 0] = run; fill[i0 + 0] = run; } run += v0;
        if (i0 + 1 < N_NODES) { row_ptr[i0 + 1] = run; fill[i0 + 1] = run; } run += v1;
        if (i0 + 2 < N_NODES) { row_ptr[i0 + 2] = run; fill[i0 + 2] = run; } run += v2;
        if (i0 + 3 < N_NODES) { row_ptr[i0 + 3] = run; fill[i0 + 3] = run; } run += v3;
        __syncthreads();
        if (tid == 0) carry_s += wsum[15];
        __syncthreads();
    }
    if (tid == 0) row_ptr[N_NODES] = carry_s;   // == N_EDGES
}

// ---------------------------------------------------------------------------
// 3) Norms: ns = clip(out_deg,1)^-0.5 ; nd = clip(in_deg,1)^-0.5
// ---------------------------------------------------------------------------
__global__ __launch_bounds__(256) void norms_k(const int* __restrict__ cnt_src,
                                               const int* __restrict__ row_ptr,
                                               float* __restrict__ ns,
                                               float* __restrict__ nd) {
    int v = blockIdx.x * 256 + threadIdx.x;
    if (v < N_NODES) {
        int od = cnt_src[v];
        int id = row_ptr[v + 1] - row_ptr[v];
        ns[v] = 1.0f / sqrtf((float)(od > 1 ? od : 1));
        nd[v] = 1.0f / sqrtf((float)(id > 1 ? id : 1));
    }
}

// ---------------------------------------------------------------------------
// 4) CSR scatter: col[pos] = src for each edge, bucketed by dst
// ---------------------------------------------------------------------------
__global__ __launch_bounds__(256) void scatter_k(const int* __restrict__ src,
                                                 const int* __restrict__ dst,
                                                 int* __restrict__ fill,
                                                 int* __restrict__ col) {
    int i = blockIdx.x * 256 + threadIdx.x;
    if (i < N_EDGES) {
        int d = dst[i];
        int p = atomicAdd(&fill[d], 1);
        col[p] = src[i];
    }
}

// ---------------------------------------------------------------------------
// 5) SpMM: out[v] = nd[v] * sum_{e in-edges(v)} ns[col[e]] * x[col[e]]
//    32 lanes per node (float4 each), 8 nodes per 256-thread block
// ---------------------------------------------------------------------------
__global__ __launch_bounds__(256) void spmm_k(const float* __restrict__ x,
                                              const int* __restrict__ row_ptr,
                                              const int* __restrict__ col,
                                              const float* __restrict__ ns,
                                              const float* __restrict__ nd,
                                              float* __restrict__ out) {
    int node = blockIdx.x * 8 + (threadIdx.x >> 5);
    if (node >= N_NODES) return;
    int lane = threadIdx.x & 31;
    int s = row_ptr[node];
    int e = row_ptr[node + 1];
    const float4* x4 = (const float4*)x;
    float4 acc = make_float4(0.f, 0.f, 0.f, 0.f);
    for (int i = s; i < e; i++) {
        int c = col[i];
        float w = ns[c];
        float4 hv = x4[c * 32 + lane];
        acc.x = fmaf(w, hv.x, acc.x);
        acc.y = fmaf(w, hv.y, acc.y);
        acc.z = fmaf(w, hv.z, acc.z);
        acc.w = fmaf(w, hv.w, acc.w);
    }
    float ndv = nd[node];
    ((float4*)out)[node * 32 + lane] =
        make_float4(acc.x * ndv, acc.y * ndv, acc.z * ndv, acc.w * ndv);
}

// ---------------------------------------------------------------------------
// 6) GEMM + bias + ReLU: out = relu(A @ W + b), A [50000 x 128], W [128 x 128]
//    64-row tile, full 128 cols per block via 2 sequential 64-col W halves.
//    LDS: As_t (A transposed, [k][r]) 32KB + Ws half [k][c] 32KB = 64KB.
//    In-place safe: each block reads only its own rows, writes at the end.
// ---------------------------------------------------------------------------
__global__ __launch_bounds__(256) void gemm_relu_k(const float* __restrict__ A,
                                                   const float* __restrict__ W,
                                                   const float* __restrict__ bias,
                                                   float* __restrict__ out) {
    __shared__ float As_t[128 * 64];   // [k][r]
    __shared__ float Ws[128 * 64];     // [k][c] (current 64-col half)
    int tid = threadIdx.x;
    int row0 = blockIdx.x * 64;

    // Stage A transposed: linear float4 id -> (r = linear&63, kg = linear>>6)
    #pragma unroll
    for (int it = 0; it < 8; it++) {
        int linear = it * 256 + tid;       // 0..2047
        int r = linear & 63;
        int kg = linear >> 6;              // 0..31 (k0 = kg*4)
        int row = row0 + r;
        float4 a = (row < N_NODES) ? ((const float4*)A)[row * 32 + kg]
                                   : make_float4(0.f, 0.f, 0.f, 0.f);
        As_t[(kg * 4 + 0) * 64 + r] = a.x;
        As_t[(kg * 4 + 1) * 64 + r] = a.y;
        As_t[(kg * 4 + 2) * 64 + r] = a.z;
        As_t[(kg * 4 + 3) * 64 + r] = a.w;
    }

    int cg = tid & 15;    // col group: c0 = cg*4 (within half)
    int rg = tid >> 4;    // 0..15   : r0 = rg*4
    float acc[2][4][4];
    #pragma unroll
    for (int h = 0; h < 2; h++)
        #pragma unroll
        for (int r = 0; r < 4; r++)
            #pragma unroll
            for (int c = 0; c < 4; c++) acc[h][r][c] = 0.f;

    for (int h = 0; h < 2; h++) {
        __syncthreads();   // As_t staged / previous half's reads done
        #pragma unroll
        for (int it = 0; it < 8; it++) {
            int linear = it * 256 + tid;   // 0..2047 float4s
            int k = linear >> 4;           // 0..127
            int c4 = linear & 15;
            ((float4*)Ws)[linear] = ((const float4*)(W + k * 128 + h * 64))[c4];
        }
        __syncthreads();
        float (*ah)[4] = acc[h];
        for (int k = 0; k < 128; k++) {
            float4 av = *(const float4*)(As_t + k * 64 + rg * 4);
            float4 wv = *(const float4*)(Ws + k * 64 + cg * 4);
            ah[0][0] = fmaf(av.x, wv.x, ah[0][0]);
            ah[0][1] = fmaf(av.x, wv.y, ah[0][1]);
            ah[0][2] = fmaf(av.x, wv.z, ah[0][2]);
            ah[0][3] = fmaf(av.x, wv.w, ah[0][3]);
            ah[1][0] = fmaf(av.y, wv.x, ah[1][0]);
            ah[1][1] = fmaf(av.y, wv.y, ah[1][1]);
            ah[1][2] = fmaf(av.y, wv.z, ah[1][2]);
            ah[1][3] = fmaf(av.y, wv.w, ah[1][3]);
            ah[2][0] = fmaf(av.z, wv.x, ah[2][0]);
            ah[2][1] = fmaf(av.z, wv.y, ah[2][1]);
            ah[2][2] = fmaf(av.z, wv.z, ah[2][2]);
            ah[2][3] = fmaf(av.z, wv.w, ah[2][3]);
            ah[3][0] = fmaf(av.w, wv.x, ah[3][0]);
            ah[3][1] = fmaf(av.w, wv.y, ah[3][1]);
            ah[3][2] = fmaf(av.w, wv.z, ah[3][2]);
            ah[3][3] = fmaf(av.w, wv.w, ah[3][3]);
        }
    }

    // Epilogue: bias + ReLU, write both halves (after all reads -> in-place ok)
    #pragma unroll
    for (int h = 0; h < 2; h++) {
        float4 bv = ((const float4*)bias)[h * 16 + cg];
        #pragma unroll
        for (int r = 0; r < 4; r++) {
            int row = row0 + rg * 4 + r;
            if (row < N_NODES) {
                float4 o;
                o.x = fmaxf(acc[h][r][0] + bv.x, 0.f);
                o.y = fmaxf(acc[h][r][1] + bv.y, 0.f);
                o.z = fmaxf(acc[h][r][2] + bv.z, 0.f);
                o.w = fmaxf(acc[h][r][3] + bv.w, 0.f);
                ((float4*)out)[row * 32 + h * 16 + cg] = o;
            }
        }
    }
}

// ---------------------------------------------------------------------------
// 7) Readout: per-graph sums (graph_ids sorted -> run-length + rare atomics)
// ---------------------------------------------------------------------------
__global__ __launch_bounds__(128) void readout_k(const float* __restrict__ h,
                                                 const int* __restrict__ gid,
                                                 float* __restrict__ hg_sum,
                                                 int* __restrict__ gcnt) {
    int t = threadIdx.x;                // feature column 0..127
    int v0 = blockIdx.x * 256;
    if (v0 >= N_NODES) return;
    int vend = v0 + 256; if (vend > N_NODES) vend = N_NODES;
    int cur = gid[v0];
    int runstart = v0;
    float acc = 0.f;
    for (int v = v0; v < vend; v++) {
        int g = gid[v];
        if (g != cur) {
            atomicAdd(&hg_sum[cur * D + t], acc);
            if (t == 0) atomicAdd(&gcnt[cur], v - runstart);
            acc = 0.f; cur = g; runstart = v;
        }
        acc += h[v * D + t];
    }
    atomicAdd(&hg_sum[cur * D + t], acc);
    if (t == 0) atomicAdd(&gcnt[cur], vend - runstart);
}

// ---------------------------------------------------------------------------
// 8) Final: hg = hg_sum/cnt ; logits = hg @ Wm + bm ; log_softmax(axis=0)
// ---------------------------------------------------------------------------
__global__ __launch_bounds__(512) void final_k(const float* __restrict__ hg_sum,
                                               const int* __restrict__ gcnt,
                                               const float* __restrict__ Wm,
                                               const float* __restrict__ bm,
                                               float* __restrict__ out) {
    __shared__ float hg[N_GRAPHS * D];
    __shared__ float lg[N_GRAPHS * D_OUT];
    __shared__ float colm[D_OUT], colls[D_OUT];
    int tid = threadIdx.x;
    for (int i = tid; i < N_GRAPHS * D; i += 512) {
        int g = i >> 7;
        float c = (float)gcnt[g];
        hg[i] = hg_sum[i] / (c > 1.f ? c : 1.f);
    }
    __syncthreads();
    if (tid < N_GRAPHS * D_OUT) {
        int g = tid / D_OUT, o = tid % D_OUT;
        float acc = bm[o];
        for (int k = 0; k < D; k++) acc = fmaf(hg[g * D + k], Wm[k * D_OUT + o], acc);
        lg[tid] = acc;
    }
    __syncthreads();
    if (tid < D_OUT) {
        float m = -1e30f;
        for (int g = 0; g < N_GRAPHS; g++) m = fmaxf(m, lg[g * D_OUT + tid]);
        float s = 0.f;
        for (int g = 0; g < N_GRAPHS; g++) s += expf(lg[g * D_OUT + tid] - m);
        colm[tid] = m; colls[tid] = logf(s);
    }
    __syncthreads();
    if (tid < N_GRAPHS * D_OUT) {
        int o = tid % D_OUT;
        out[tid] = lg[tid] - colm[o] - colls[o];
    }
}

// ---------------------------------------------------------------------------
// Launch
// ---------------------------------------------------------------------------
extern "C" void kernel_launch(void* const* d_in, const int* in_sizes, int n_in,
                              void* d_out, int out_size, void* d_ws, size_t ws_size,
                              hipStream_t stream) {
    const float* h_in = (const float*)d_in[0];
    const int*   src  = (const int*)d_in[1];
    const int*   dst  = (const int*)d_in[2];
    const int*   gid  = (const int*)d_in[3];
    const float* W1 = (const float*)d_in[4];  const float* b1 = (const float*)d_in[5];
    const float* W2 = (const float*)d_in[6];  const float* b2 = (const float*)d_in[7];
    const float* W3 = (const float*)d_in[8];  const float* b3 = (const float*)d_in[9];
    const float* Wm = (const float*)d_in[10]; const float* bm = (const float*)d_in[11];

    char* ws = (char*)d_ws;
    // layout (16B aligned):
    int*   cnt     = (int*)(ws + 0);          //  50000 ints  (dst histogram)
    int*   cnt_src = (int*)(ws + 200000);     //  50000 ints
    int*   gcnt    = (int*)(ws + 400000);     //  64 ints
    float* hg_sum  = (float*)(ws + 400256);   //  6400 floats
    // zero region = [0, 425856)
    int*   row_ptr = (int*)(ws + 425856);     //  50001 ints (pad to 50004)
    int*   fill    = (int*)(ws + 625872);     //  50000 ints
    int*   col     = (int*)(ws + 825872);     //  800000 ints
    float* ns      = (float*)(ws + 4025872);  //  50000 floats
    float* nd      = (float*)(ws + 4225872);  //  50000 floats
    float* buf0    = (float*)(ws + 4425872);  //  6.4M floats
    float* buf1    = (float*)(ws + 30025872); //  6.4M floats
    // total: 55,625,872 bytes

    hipMemsetAsync(ws, 0, 425856, stream);

    hist_edges<<<3125, 256, 0, stream>>>(src, dst, cnt, cnt_src);
    scan_k<<<1, 1024, 0, stream>>>(cnt, row_ptr, fill);
    norms_k<<<196, 256, 0, stream>>>(cnt_src, row_ptr, ns, nd);
    scatter_k<<<3125, 256, 0, stream>>>(src, dst, fill, col);

    // layer 1
    spmm_k<<<6250, 256, 0, stream>>>(h_in, row_ptr, col, ns, nd, buf0);
    gemm_relu_k<<<782, 256, 0, stream>>>(buf0, W1, b1, buf0);
    // layer 2
    spmm_k<<<6250, 256, 0, stream>>>(buf0, row_ptr, col, ns, nd, buf1);
    gemm_relu_k<<<782, 256, 0, stream>>>(buf1, W2, b2, buf1);
    // layer 3
    spmm_k<<<6250, 256, 0, stream>>>(buf1, row_ptr, col, ns, nd, buf0);
    gemm_relu_k<<<782, 256, 0, stream>>>(buf0, W3, b3, buf0);

    readout_k<<<196, 128, 0, stream>>>(buf0, gid, hg_sum, gcnt);
    final_k<<<1, 512, 0, stream>>>(hg_sum, gcnt, Wm, bm, (float*)d_out);
}

// Round 2
// 576.887 us; speedup vs baseline: 1.0936x; 1.0936x over previous
//
#include <hip/hip_runtime.h>

#define N_NODES 50000
#define N_EDGES 800000
#define N_GRAPHS 50
#define D 128
#define D_OUT 10

// ---------------------------------------------------------------------------
// 1) Degree histograms: cnt_dst (in-deg -> CSR row counts), cnt_src (out-deg)
// ---------------------------------------------------------------------------
__global__ __launch_bounds__(256) void hist_edges(const int* __restrict__ src,
                                                  const int* __restrict__ dst,
                                                  int* __restrict__ cnt_dst,
                                                  int* __restrict__ cnt_src) {
    int i = blockIdx.x * 256 + threadIdx.x;
    if (i < N_EDGES) {
        atomicAdd(&cnt_dst[dst[i]], 1);
        atomicAdd(&cnt_src[src[i]], 1);
    }
}

// ---------------------------------------------------------------------------
// 2) Single-block exclusive scan of cnt -> row_ptr; also rewrites cnt in-place
//    as the scatter cursor ("fill"). Safe: each thread reads its own indices
//    before writing them; cross-tile indices are disjoint.
// ---------------------------------------------------------------------------
__global__ __launch_bounds__(1024) void scan_k(int* __restrict__ cnt,
                                               int* __restrict__ row_ptr) {
    __shared__ int wsum[16];
    __shared__ int carry_s;
    int tid = threadIdx.x;
    int lane = tid & 63, wid = tid >> 6;
    if (tid == 0) carry_s = 0;
    __syncthreads();
    for (int base = 0; base < N_NODES; base += 4096) {
        int i0 = base + tid * 4;
        int v0 = (i0 + 0 < N_NODES) ? cnt[i0 + 0] : 0;
        int v1 = (i0 + 1 < N_NODES) ? cnt[i0 + 1] : 0;
        int v2 = (i0 + 2 < N_NODES) ? cnt[i0 + 2] : 0;
        int v3 = (i0 + 3 < N_NODES) ? cnt[i0 + 3] : 0;
        int s = v0 + v1 + v2 + v3;
        int x = s;
        #pragma unroll
        for (int d = 1; d < 64; d <<= 1) {
            int y = __shfl_up(x, d, 64);
            if (lane >= d) x += y;
        }
        if (lane == 63) wsum[wid] = x;
        __syncthreads();
        if (wid == 0) {
            int t = (lane < 16) ? wsum[lane] : 0;
            #pragma unroll
            for (int d = 1; d < 16; d <<= 1) {
                int y = __shfl_up(t, d, 64);
                if (lane >= d) t += y;
            }
            if (lane < 16) wsum[lane] = t;
        }
        __syncthreads();
        int woff = (wid == 0) ? 0 : wsum[wid - 1];
        int excl = carry_s + woff + (x - s);
        int run = excl;
        if (i0 + 0 < N_NODES) { row_ptr[i0 + 0] = run; cnt[i0 + 0] = run; } run += v0;
        if (i0 + 1 < N_NODES) { row_ptr[i0 + 1] = run; cnt[i0 + 1] = run; } run += v1;
        if (i0 + 2 < N_NODES) { row_ptr[i0 + 2] = run; cnt[i0 + 2] = run; } run += v2;
        if (i0 + 3 < N_NODES) { row_ptr[i0 + 3] = run; cnt[i0 + 3] = run; } run += v3;
        __syncthreads();
        if (tid == 0) carry_s += wsum[15];
        __syncthreads();
    }
    if (tid == 0) row_ptr[N_NODES] = carry_s;   // == N_EDGES
}

// ---------------------------------------------------------------------------
// 3) Norms: ns = clip(out_deg,1)^-0.5 ; nd = clip(in_deg,1)^-0.5
// ---------------------------------------------------------------------------
__global__ __launch_bounds__(256) void norms_k(const int* __restrict__ cnt_src,
                                               const int* __restrict__ row_ptr,
                                               float* __restrict__ ns,
                                               float* __restrict__ nd) {
    int v = blockIdx.x * 256 + threadIdx.x;
    if (v < N_NODES) {
        int od = cnt_src[v];
        int id = row_ptr[v + 1] - row_ptr[v];
        ns[v] = 1.0f / sqrtf((float)(od > 1 ? od : 1));
        nd[v] = 1.0f / sqrtf((float)(id > 1 ? id : 1));
    }
}

// ---------------------------------------------------------------------------
// 4) CSR scatter: col[pos]=src, and (optionally) wgt[pos]=ns[src] pre-fused.
//    "fill" is the scan-rewritten cnt buffer.
// ---------------------------------------------------------------------------
template <bool USE_W>
__global__ __launch_bounds__(256) void scatter_k(const int* __restrict__ src,
                                                 const int* __restrict__ dst,
                                                 int* __restrict__ fill,
                                                 int* __restrict__ col,
                                                 const float* __restrict__ ns,
                                                 float* __restrict__ wgt) {
    int i = blockIdx.x * 256 + threadIdx.x;
    if (i < N_EDGES) {
        int s = src[i];
        int d = dst[i];
        int p = atomicAdd(&fill[d], 1);
        col[p] = s;
        if (USE_W) wgt[p] = ns[s];
    }
}

// ---------------------------------------------------------------------------
// 5) SpMM: out[v] = nd[v] * sum_{e in-edges(v)} ns[col[e]] * x[col[e]]
//    32 lanes per node (float4 each), 8 nodes per 256-thread block.
//    4-edge unroll, 2 accumulators -> 4 gathers in flight per chain.
// ---------------------------------------------------------------------------
template <bool USE_W>
__global__ __launch_bounds__(256) void spmm_k(const float* __restrict__ x,
                                              const int* __restrict__ row_ptr,
                                              const int* __restrict__ col,
                                              const float* __restrict__ wgt,
                                              const float* __restrict__ ns,
                                              const float* __restrict__ nd,
                                              float* __restrict__ out) {
    int node = blockIdx.x * 8 + (threadIdx.x >> 5);
    if (node >= N_NODES) return;
    int lane = threadIdx.x & 31;
    int s = row_ptr[node];
    int e = row_ptr[node + 1];
    const float4* x4 = (const float4*)x;
    float4 a0 = make_float4(0.f, 0.f, 0.f, 0.f);
    float4 a1 = make_float4(0.f, 0.f, 0.f, 0.f);
    int i = s;
    for (; i + 4 <= e; i += 4) {
        int c0 = col[i], c1 = col[i + 1], c2 = col[i + 2], c3 = col[i + 3];
        float w0, w1, w2, w3;
        if (USE_W) {
            w0 = wgt[i]; w1 = wgt[i + 1]; w2 = wgt[i + 2]; w3 = wgt[i + 3];
        } else {
            w0 = ns[c0]; w1 = ns[c1]; w2 = ns[c2]; w3 = ns[c3];
        }
        float4 h0 = x4[c0 * 32 + lane];
        float4 h1 = x4[c1 * 32 + lane];
        float4 h2 = x4[c2 * 32 + lane];
        float4 h3 = x4[c3 * 32 + lane];
        a0.x = fmaf(w0, h0.x, a0.x); a0.y = fmaf(w0, h0.y, a0.y);
        a0.z = fmaf(w0, h0.z, a0.z); a0.w = fmaf(w0, h0.w, a0.w);
        a1.x = fmaf(w1, h1.x, a1.x); a1.y = fmaf(w1, h1.y, a1.y);
        a1.z = fmaf(w1, h1.z, a1.z); a1.w = fmaf(w1, h1.w, a1.w);
        a0.x = fmaf(w2, h2.x, a0.x); a0.y = fmaf(w2, h2.y, a0.y);
        a0.z = fmaf(w2, h2.z, a0.z); a0.w = fmaf(w2, h2.w, a0.w);
        a1.x = fmaf(w3, h3.x, a1.x); a1.y = fmaf(w3, h3.y, a1.y);
        a1.z = fmaf(w3, h3.z, a1.z); a1.w = fmaf(w3, h3.w, a1.w);
    }
    for (; i < e; i++) {
        int c = col[i];
        float w = USE_W ? wgt[i] : ns[c];
        float4 hv = x4[c * 32 + lane];
        a0.x = fmaf(w, hv.x, a0.x); a0.y = fmaf(w, hv.y, a0.y);
        a0.z = fmaf(w, hv.z, a0.z); a0.w = fmaf(w, hv.w, a0.w);
    }
    float ndv = nd[node];
    ((float4*)out)[node * 32 + lane] =
        make_float4((a0.x + a1.x) * ndv, (a0.y + a1.y) * ndv,
                    (a0.z + a1.z) * ndv, (a0.w + a1.w) * ndv);
}

// ---------------------------------------------------------------------------
// 6) GEMM + bias + ReLU: out = relu(A @ W + b), A [50000 x 128], W [128 x 128]
// ---------------------------------------------------------------------------
__global__ __launch_bounds__(256) void gemm_relu_k(const float* __restrict__ A,
                                                   const float* __restrict__ W,
                                                   const float* __restrict__ bias,
                                                   float* __restrict__ out) {
    __shared__ float As_t[128 * 64];   // [k][r]
    __shared__ float Ws[128 * 64];     // [k][c] (current 64-col half)
    int tid = threadIdx.x;
    int row0 = blockIdx.x * 64;

    #pragma unroll
    for (int it = 0; it < 8; it++) {
        int linear = it * 256 + tid;       // 0..2047
        int r = linear & 63;
        int kg = linear >> 6;              // 0..31 (k0 = kg*4)
        int row = row0 + r;
        float4 a = (row < N_NODES) ? ((const float4*)A)[row * 32 + kg]
                                   : make_float4(0.f, 0.f, 0.f, 0.f);
        As_t[(kg * 4 + 0) * 64 + r] = a.x;
        As_t[(kg * 4 + 1) * 64 + r] = a.y;
        As_t[(kg * 4 + 2) * 64 + r] = a.z;
        As_t[(kg * 4 + 3) * 64 + r] = a.w;
    }

    int cg = tid & 15;    // col group: c0 = cg*4 (within half)
    int rg = tid >> 4;    // 0..15   : r0 = rg*4
    float acc[2][4][4];
    #pragma unroll
    for (int h = 0; h < 2; h++)
        #pragma unroll
        for (int r = 0; r < 4; r++)
            #pragma unroll
            for (int c = 0; c < 4; c++) acc[h][r][c] = 0.f;

    for (int h = 0; h < 2; h++) {
        __syncthreads();
        #pragma unroll
        for (int it = 0; it < 8; it++) {
            int linear = it * 256 + tid;   // 0..2047 float4s
            int k = linear >> 4;
            int c4 = linear & 15;
            ((float4*)Ws)[linear] = ((const float4*)(W + k * 128 + h * 64))[c4];
        }
        __syncthreads();
        float (*ah)[4] = acc[h];
        for (int k = 0; k < 128; k++) {
            float4 av = *(const float4*)(As_t + k * 64 + rg * 4);
            float4 wv = *(const float4*)(Ws + k * 64 + cg * 4);
            ah[0][0] = fmaf(av.x, wv.x, ah[0][0]);
            ah[0][1] = fmaf(av.x, wv.y, ah[0][1]);
            ah[0][2] = fmaf(av.x, wv.z, ah[0][2]);
            ah[0][3] = fmaf(av.x, wv.w, ah[0][3]);
            ah[1][0] = fmaf(av.y, wv.x, ah[1][0]);
            ah[1][1] = fmaf(av.y, wv.y, ah[1][1]);
            ah[1][2] = fmaf(av.y, wv.z, ah[1][2]);
            ah[1][3] = fmaf(av.y, wv.w, ah[1][3]);
            ah[2][0] = fmaf(av.z, wv.x, ah[2][0]);
            ah[2][1] = fmaf(av.z, wv.y, ah[2][1]);
            ah[2][2] = fmaf(av.z, wv.z, ah[2][2]);
            ah[2][3] = fmaf(av.z, wv.w, ah[2][3]);
            ah[3][0] = fmaf(av.w, wv.x, ah[3][0]);
            ah[3][1] = fmaf(av.w, wv.y, ah[3][1]);
            ah[3][2] = fmaf(av.w, wv.z, ah[3][2]);
            ah[3][3] = fmaf(av.w, wv.w, ah[3][3]);
        }
    }

    #pragma unroll
    for (int h = 0; h < 2; h++) {
        float4 bv = ((const float4*)bias)[h * 16 + cg];
        #pragma unroll
        for (int r = 0; r < 4; r++) {
            int row = row0 + rg * 4 + r;
            if (row < N_NODES) {
                float4 o;
                o.x = fmaxf(acc[h][r][0] + bv.x, 0.f);
                o.y = fmaxf(acc[h][r][1] + bv.y, 0.f);
                o.z = fmaxf(acc[h][r][2] + bv.z, 0.f);
                o.w = fmaxf(acc[h][r][3] + bv.w, 0.f);
                ((float4*)out)[row * 32 + h * 16 + cg] = o;
            }
        }
    }
}

// ---------------------------------------------------------------------------
// 7) Fused projection + readout: p[v,:] = h[v,:] @ Wm  (mean/bias applied in
//    final_k). 4 threads per node; segmented wave-scan over sorted graph_ids;
//    only run-tail lanes do global atomics (~1-2 per wave).
// ---------------------------------------------------------------------------
__global__ __launch_bounds__(256) void proj_readout_k(const float* __restrict__ h,
                                                      const int* __restrict__ gid,
                                                      const float* __restrict__ Wm,
                                                      float* __restrict__ hgp,
                                                      int* __restrict__ gcnt) {
    // Wm transposed with +4 skew per 32-k group to break 4-way b128 conflicts:
    // Wmt[o*144 + k + 4*(k>>5)] = Wm[k*10 + o]
    __shared__ float Wmt[10 * 144];
    int tid = threadIdx.x;
    for (int i = tid; i < 1280; i += 256) {
        int k = i / 10, o = i % 10;
        Wmt[o * 144 + k + 4 * (k >> 5)] = Wm[i];
    }
    __syncthreads();

    int v = blockIdx.x * 64 + (tid >> 2);
    int quarter = tid & 3;                  // owns k = quarter*32 .. +32
    int lane = tid & 63;

    float acc[D_OUT];
    #pragma unroll
    for (int o = 0; o < D_OUT; o++) acc[o] = 0.f;
    int g = -1;
    int cnt = 0;
    if (v < N_NODES) {
        g = gid[v];
        cnt = (quarter == 0) ? 1 : 0;
        const float4* h4 = (const float4*)h + v * 32 + quarter * 8;
        const float* wbase = Wmt + quarter * 36;   // k-offset quarter*32 + skew quarter*4
        #pragma unroll
        for (int kk = 0; kk < 8; kk++) {
            float4 hv = h4[kk];
            #pragma unroll
            for (int o = 0; o < D_OUT; o++) {
                float4 w = *(const float4*)(wbase + o * 144 + kk * 4);
                acc[o] += hv.x * w.x + hv.y * w.y + hv.z * w.z + hv.w * w.w;
            }
        }
    }

    // Segmented inclusive scan across the wave (valid because gid is sorted:
    // g[lane-d]==g[lane] implies the whole intermediate range is equal).
    #pragma unroll
    for (int d = 1; d < 64; d <<= 1) {
        int gp = __shfl_up(g, d, 64);
        int cp = __shfl_up(cnt, d, 64);
        bool take = (lane >= d) && (gp == g);
        #pragma unroll
        for (int o = 0; o < D_OUT; o++) {
            float ap = __shfl_up(acc[o], d, 64);
            if (take) acc[o] += ap;
        }
        if (take) cnt += cp;
    }
    int gn = __shfl_down(g, 1, 64);
    bool tail = (lane == 63) || (gn != g);
    if (tail && g >= 0) {
        #pragma unroll
        for (int o = 0; o < D_OUT; o++) atomicAdd(&hgp[g * D_OUT + o], acc[o]);
        if (cnt > 0) atomicAdd(&gcnt[g], cnt);
    }
}

// ---------------------------------------------------------------------------
// 8) Final: logits = hgp/cnt + bm ; log_softmax over axis 0 (graphs)
// ---------------------------------------------------------------------------
__global__ __launch_bounds__(512) void final_k(const float* __restrict__ hgp,
                                               const int* __restrict__ gcnt,
                                               const float* __restrict__ bm,
                                               float* __restrict__ out) {
    __shared__ float lg[N_GRAPHS * D_OUT];
    __shared__ float colm[D_OUT], colls[D_OUT];
    int tid = threadIdx.x;
    if (tid < N_GRAPHS * D_OUT) {
        int g = tid / D_OUT, o = tid % D_OUT;
        float c = (float)gcnt[g];
        lg[tid] = hgp[tid] / (c > 1.f ? c : 1.f) + bm[o];
    }
    __syncthreads();
    if (tid < D_OUT) {
        float m = -1e30f;
        for (int g = 0; g < N_GRAPHS; g++) m = fmaxf(m, lg[g * D_OUT + tid]);
        float s = 0.f;
        for (int g = 0; g < N_GRAPHS; g++) s += expf(lg[g * D_OUT + tid] - m);
        colm[tid] = m; colls[tid] = logf(s);
    }
    __syncthreads();
    if (tid < N_GRAPHS * D_OUT) {
        int o = tid % D_OUT;
        out[tid] = lg[tid] - colm[o] - colls[o];
    }
}

// ---------------------------------------------------------------------------
// Launch
// ---------------------------------------------------------------------------
extern "C" void kernel_launch(void* const* d_in, const int* in_sizes, int n_in,
                              void* d_out, int out_size, void* d_ws, size_t ws_size,
                              hipStream_t stream) {
    const float* h_in = (const float*)d_in[0];
    const int*   src  = (const int*)d_in[1];
    const int*   dst  = (const int*)d_in[2];
    const int*   gid  = (const int*)d_in[3];
    const float* W1 = (const float*)d_in[4];  const float* b1 = (const float*)d_in[5];
    const float* W2 = (const float*)d_in[6];  const float* b2 = (const float*)d_in[7];
    const float* W3 = (const float*)d_in[8];  const float* b3 = (const float*)d_in[9];
    const float* Wm = (const float*)d_in[10]; const float* bm = (const float*)d_in[11];

    char* ws = (char*)d_ws;
    // layout (all offsets 16B-aligned):
    int*   cnt     = (int*)(ws + 0);          //  50000 ints; becomes scatter cursor
    int*   cnt_src = (int*)(ws + 200000);     //  50000 ints
    int*   gcnt    = (int*)(ws + 400000);     //  64 ints
    float* hgp     = (float*)(ws + 400256);   //  500 floats (pad to 512)
    // zero region = [0, 402304)
    int*   row_ptr = (int*)(ws + 402304);     //  50001 ints (pad 50004)
    int*   col     = (int*)(ws + 602320);     //  800000 ints
    float* ns      = (float*)(ws + 3802320);  //  50000 floats
    float* nd      = (float*)(ws + 4002320);  //  50000 floats
    float* buf0    = (float*)(ws + 4202320);  //  6.4M floats
    float* buf1    = (float*)(ws + 29802320); //  6.4M floats
    float* wgt     = (float*)(ws + 55402320); //  800000 floats (optional)
    bool use_w = ws_size >= (size_t)58602320;

    hipMemsetAsync(ws, 0, 402304, stream);

    hist_edges<<<3125, 256, 0, stream>>>(src, dst, cnt, cnt_src);
    scan_k<<<1, 1024, 0, stream>>>(cnt, row_ptr);
    norms_k<<<196, 256, 0, stream>>>(cnt_src, row_ptr, ns, nd);
    if (use_w) {
        scatter_k<true><<<3125, 256, 0, stream>>>(src, dst, cnt, col, ns, wgt);
        spmm_k<true><<<6250, 256, 0, stream>>>(h_in, row_ptr, col, wgt, ns, nd, buf0);
        gemm_relu_k<<<782, 256, 0, stream>>>(buf0, W1, b1, buf0);
        spmm_k<true><<<6250, 256, 0, stream>>>(buf0, row_ptr, col, wgt, ns, nd, buf1);
        gemm_relu_k<<<782, 256, 0, stream>>>(buf1, W2, b2, buf1);
        spmm_k<true><<<6250, 256, 0, stream>>>(buf1, row_ptr, col, wgt, ns, nd, buf0);
        gemm_relu_k<<<782, 256, 0, stream>>>(buf0, W3, b3, buf0);
    } else {
        scatter_k<false><<<3125, 256, 0, stream>>>(src, dst, cnt, col, ns, nullptr);
        spmm_k<false><<<6250, 256, 0, stream>>>(h_in, row_ptr, col, nullptr, ns, nd, buf0);
        gemm_relu_k<<<782, 256, 0, stream>>>(buf0, W1, b1, buf0);
        spmm_k<false><<<6250, 256, 0, stream>>>(buf0, row_ptr, col, nullptr, ns, nd, buf1);
        gemm_relu_k<<<782, 256, 0, stream>>>(buf1, W2, b2, buf1);
        spmm_k<false><<<6250, 256, 0, stream>>>(buf1, row_ptr, col, nullptr, ns, nd, buf0);
        gemm_relu_k<<<782, 256, 0, stream>>>(buf0, W3, b3, buf0);
    }

    proj_readout_k<<<782, 256, 0, stream>>>(buf0, gid, Wm, hgp, gcnt);
    final_k<<<1, 512, 0, stream>>>(hgp, gcnt, bm, (float*)d_out);
}